// Round 11
// baseline (635.410 us; speedup 1.0000x reference)
//
#include <hip/hip_runtime.h>
#include <math.h>

#define BATCH 128
#define T 250
#define D_IN 700
#define H 256
#define D_OUT 20
#define RING 16

typedef float v2f __attribute__((ext_vector_type(2)));
typedef __attribute__((ext_vector_type(8))) short bf16x8;
typedef __attribute__((ext_vector_type(4))) float f32x4;
typedef __attribute__((ext_vector_type(4))) unsigned u32x4;

static __device__ __forceinline__ unsigned short f2b(float f) {
    unsigned u = __float_as_uint(f);
    u += 0x7FFFu + ((u >> 16) & 1u);
    return (unsigned short)(u >> 16);
}

// PA partial index (C1 cols, 8 f32/lane at stride 10) — R8-proven.
#define PIDX(c) (10 * ((c) >> 3) + ((c) & 7))
// PB partial index (compacted C2 cols, 4 f32/lane at stride 6) — R9-proven.
#define QIDX(c) (6 * ((c) >> 2) + ((c) & 3))

// ---------------------------------------------------------------------------
// Workspace:
//   Ub    [32001][256] bf16  (pad row for u-prefetch overrun)
//   C1b   [257][512] bf16    p<256: W12T[k][p]; p>=256: W11T[k][p-256]
//   C2b   [257][288] bf16    p<256: W22T[k][p]; p in [256,276): Wo[p-256][k]
//   Wi1p  [256][704] bf16
//   G12   [128][RING][256] f32   A->B stream (agent-scope/L3-coherent)
//   prog  [128] int   A's published-step counter (prog=t: steps <t ready)
//   bdone [128] int   B's window counter (ring overwrite throttle)
//
// R11: split each batch element across TWO CUs. A-block (even blockIdx):
// layer-1 recurrence, self-contained (needs only its own g11), publishes
// g12(t) to the G12 ring. B-block (odd): layer 2 (lag 3 windows) + output,
// prefetches g12 one window ahead of use (latency hidden). No cross-block
// barrier — forward-only dataflow with monotonic flags. Per-CU issue work
// halves vs R8/R10 (the measured pole). R10's LDS-staged C2 kept in B.
// ---------------------------------------------------------------------------
#define N_C1 (257 * 512)
#define N_C2 (257 * 288)
#define N_WP (256 * 704)

__global__ void prep_k(const float* __restrict__ Wi1, const float* __restrict__ W11,
                       const float* __restrict__ W12, const float* __restrict__ W22,
                       const float* __restrict__ Wo,
                       unsigned short* __restrict__ Wi1p, unsigned short* __restrict__ C1,
                       unsigned short* __restrict__ C2) {
    int idx = blockIdx.x * 256 + threadIdx.x;
    if (idx < N_C1) {
        int k = idx >> 9, p = idx & 511;
        float v = 0.f;
        if (k < H) v = (p < 256) ? W12[p * H + k] : W11[(p - 256) * H + k];
        C1[idx] = f2b(v);
        return;
    }
    idx -= N_C1;
    if (idx < N_C2) {
        int k = idx / 288, p = idx - k * 288;
        float v = 0.f;
        if (k < H) {
            if (p < 256) v = W22[p * H + k];
            else if (p - 256 < D_OUT) v = Wo[(p - 256) * H + k];
        }
        C2[idx] = f2b(v);
        return;
    }
    idx -= N_C2;
    if (idx < N_WP) {
        int h = idx / 704, k = idx - h * 704;
        Wi1p[idx] = (k < D_IN) ? f2b(Wi1[h * D_IN + k]) : (unsigned short)0;
    }
}

// ---------------------------------------------------------------------------
// U = x @ Wi1^T + bi1 via MFMA — R8-proven; epilogue now stores bf16.
// ---------------------------------------------------------------------------
__global__ __launch_bounds__(256) void gemm_u_k(const float* __restrict__ x,
                                                const unsigned short* __restrict__ Wi1p,
                                                const float* __restrict__ bi1,
                                                unsigned short* __restrict__ Ub) {
    const int lane = threadIdx.x & 63;
    const int wv = threadIdx.x >> 6;
    const int quad = lane >> 4;
    const int nl = lane & 15;
    const int mbase = blockIdx.x * 64 + wv * 16;
    const int m = mbase + nl;

    f32x4 acc[16];
#pragma unroll
    for (int i = 0; i < 16; ++i) acc[i] = (f32x4)(0.f);

    float bias[16];
#pragma unroll
    for (int nt = 0; nt < 16; ++nt) bias[nt] = bi1[nt * 16 + nl];

    const float* xrow = x + (size_t)m * D_IN;
    const unsigned short* brow = Wi1p + nl * 704 + quad * 8;

    for (int k0 = 0; k0 < 704; k0 += 32) {
        int ka = k0 + quad * 8;
        int ka2 = (ka + 4 <= 696) ? ka + 4 : 696;
        float4 q0 = *(const float4*)(xrow + ka);
        float4 q1 = *(const float4*)(xrow + ka2);
        bf16x8 af;
        af[0] = (short)f2b(q0.x); af[1] = (short)f2b(q0.y);
        af[2] = (short)f2b(q0.z); af[3] = (short)f2b(q0.w);
        af[4] = (short)f2b(q1.x); af[5] = (short)f2b(q1.y);
        af[6] = (short)f2b(q1.z); af[7] = (short)f2b(q1.w);

        const unsigned short* bp = brow + k0;
        bf16x8 bf[16];
#pragma unroll
        for (int nt = 0; nt < 16; ++nt)
            bf[nt] = *(const bf16x8*)(bp + nt * 16 * 704);
#pragma unroll
        for (int nt = 0; nt < 16; ++nt)
            acc[nt] = __builtin_amdgcn_mfma_f32_16x16x32_bf16(af, bf[nt], acc[nt], 0, 0, 0);
    }

#pragma unroll
    for (int nt = 0; nt < 16; ++nt) {
#pragma unroll
        for (int r = 0; r < 4; ++r) {
            Ub[(size_t)(mbase + quad * 4 + r) * H + nt * 16 + nl] =
                f2b(acc[nt][r] + bias[nt]);
        }
    }
}

// ---------------------------------------------------------------------------
// A-gather (C1, 1KB rows, lane owns 8 cols) — R8-proven.
// ---------------------------------------------------------------------------
static __device__ __forceinline__ void ld8b(const unsigned* __restrict__ L, int c,
                                            const unsigned short* __restrict__ Cb,
                                            unsigned l8, u32x4* b) {
    uint4 ia = *(const uint4*)(L + c);
    uint4 ib = *(const uint4*)(L + c + 4);
    unsigned I[8] = {ia.x, ia.y, ia.z, ia.w, ib.x, ib.y, ib.z, ib.w};
#pragma unroll
    for (int jj = 0; jj < 8; ++jj)
        b[jj] = *(const u32x4*)(Cb + ((unsigned)I[jj] << 9) + l8);
}

static __device__ __forceinline__ void acc8b(const u32x4* b, v2f* a) {
#pragma unroll
    for (int jj = 0; jj < 8; ++jj) {
#pragma unroll
        for (int q = 0; q < 4; ++q) {
            unsigned u = b[jj][q];
            v2f t;
            t.x = __uint_as_float(u << 16);
            t.y = __uint_as_float(u & 0xffff0000u);
            a[q] += t;
        }
    }
}

static __device__ __forceinline__ void gatherB(const unsigned* __restrict__ L, int n,
                                               const unsigned short* __restrict__ Cb,
                                               unsigned l8, v2f* a) {
    a[0] = (v2f)(0.f); a[1] = (v2f)(0.f); a[2] = (v2f)(0.f); a[3] = (v2f)(0.f);
    int nr = (n + 7) & ~7;
    if (nr == 0) return;
    u32x4 x[8], y[8];
    ld8b(L, 0, Cb, l8, x);
    if (nr == 8) { acc8b(x, a); return; }
    ld8b(L, 8, Cb, l8, y);
    int c = 16;
    for (; c + 16 <= nr; c += 16) {
        acc8b(x, a); ld8b(L, c, Cb, l8, x);
        acc8b(y, a); ld8b(L, c + 8, Cb, l8, y);
    }
    if (nr - c == 8) {
        acc8b(x, a); ld8b(L, c, Cb, l8, x);
        acc8b(y, a); acc8b(x, a);
    } else {
        acc8b(x, a); acc8b(y, a);
    }
}

// ---------------------------------------------------------------------------
// B-gather (compacted 576B rows; global or LDS source) — R10-proven.
// ---------------------------------------------------------------------------
static __device__ __forceinline__ void ld8c(const unsigned* __restrict__ L, int c,
                                            const unsigned short* Cb,
                                            unsigned mo, unsigned ao,
                                            uint2* m, unsigned* av) {
    uint4 ia = *(const uint4*)(L + c);
    uint4 ib = *(const uint4*)(L + c + 4);
    unsigned I[8] = {ia.x, ia.y, ia.z, ia.w, ib.x, ib.y, ib.z, ib.w};
#pragma unroll
    for (int jj = 0; jj < 8; ++jj) {
        const unsigned short* p = Cb + (unsigned)I[jj] * 288u;
        m[jj] = *(const uint2*)(p + mo);
        av[jj] = *(const unsigned*)(p + ao);
    }
}

static __device__ __forceinline__ void acc8c(const uint2* m, const unsigned* av,
                                             v2f* g, v2f& aA) {
#pragma unroll
    for (int jj = 0; jj < 8; ++jj) {
        unsigned u0 = m[jj].x, u1 = m[jj].y, uA = av[jj];
        v2f t0, t1, tA;
        t0.x = __uint_as_float(u0 << 16); t0.y = __uint_as_float(u0 & 0xffff0000u);
        t1.x = __uint_as_float(u1 << 16); t1.y = __uint_as_float(u1 & 0xffff0000u);
        tA.x = __uint_as_float(uA << 16); tA.y = __uint_as_float(uA & 0xffff0000u);
        g[0] += t0; g[1] += t1; aA += tA;
    }
}

static __device__ __forceinline__ void gather2(const unsigned* __restrict__ L, int n,
                                               const unsigned short* Cb,
                                               unsigned mo, unsigned ao,
                                               v2f* g, v2f& aA) {
    g[0] = (v2f)(0.f); g[1] = (v2f)(0.f); aA = (v2f)(0.f);
    int nr = (n + 7) & ~7;
    if (nr == 0) return;
    uint2 xm[8], ym[8]; unsigned xa[8], ya[8];
    ld8c(L, 0, Cb, mo, ao, xm, xa);
    if (nr == 8) { acc8c(xm, xa, g, aA); return; }
    ld8c(L, 8, Cb, mo, ao, ym, ya);
    int c = 16;
    for (; c + 16 <= nr; c += 16) {
        acc8c(xm, xa, g, aA); ld8c(L, c, Cb, mo, ao, xm, xa);
        acc8c(ym, ya, g, aA); ld8c(L, c + 8, Cb, mo, ao, ym, ya);
    }
    if (nr - c == 8) {
        acc8c(xm, xa, g, aA); ld8c(L, c, Cb, mo, ao, xm, xa);
        acc8c(ym, ya, g, aA); acc8c(xm, xa, g, aA);
    } else {
        acc8c(xm, xa, g, aA); acc8c(ym, ya, g, aA);
    }
}

// ---------------------------------------------------------------------------
// Recurrent: 256 blocks (2 per batch element, 4 waves each).
// Even blockIdx = A (layer 1), odd = B (layer 2 + output, lag 3 windows).
// ---------------------------------------------------------------------------
__global__ __launch_bounds__(256, 1) void recurrent_k(
    const unsigned short* __restrict__ Ub,
    const float* __restrict__ mem1_0, const float* __restrict__ mem2_0,
    const float* __restrict__ memo_0,
    const float* __restrict__ b11v, const float* __restrict__ b12v,
    const float* __restrict__ b22v, const float* __restrict__ bov,
    const float* __restrict__ tau_adp_h1, const float* __restrict__ tau_adp_h2,
    const float* __restrict__ tau_m_h1, const float* __restrict__ tau_m_h2,
    const float* __restrict__ tau_m_o,
    const unsigned short* __restrict__ C1b, const unsigned short* __restrict__ C2b,
    float* __restrict__ G12all, int* __restrict__ prog, int* __restrict__ bdone,
    float* __restrict__ out)
{
    const int tid = threadIdx.x;
    const int lane = tid & 63;
    const int wt = tid >> 6;                 // wave 0..3
    const int bi = blockIdx.x >> 1;
    const bool isA = (blockIdx.x & 1) == 0;
    const int j = (wt << 6) + lane;          // owned neuron / publish col

    __shared__ float PA[4][2][640];                         // 20480 B (A)
    __shared__ float PB[4][2][432];                         // 13824 B (B)
    __shared__ __align__(16) unsigned short C2L[193 * 288]; // 111168 B (B)
    __shared__ __align__(16) unsigned listsA[4][128];
    __shared__ __align__(16) unsigned listsB[4][128];

    float* G12 = G12all + (size_t)bi * RING * 256;
    int* progp = prog + bi;
    int* bdonep = bdone + bi;
    const unsigned long long below = (1ull << lane) - 1ull;

    if (isA) {
        for (int i = tid; i < 4 * 2 * 640; i += 256) ((float*)PA)[i] = 0.f;

        float mem1 = mem1_0[bi * H + j];
        float al1 = __expf(-1.f / tau_m_h1[j]);
        float ro1 = __expf(-1.f / tau_adp_h1[j]);
        float oma1 = 1.f - al1, omr1 = 1.f - ro1;
        float b11p = b11v[j];
        float b1 = 0.01f, spk1 = 0.f;

        const unsigned short* Upb = Ub + (size_t)bi * T * H + j;
        unsigned short ucur = *Upb;
        const int pidx_self = 320 + PIDX(j);   // g11 col 256+j
        const int pub_pi = PIDX(j);            // g12 col j
        int bd_c = 0;
        __syncthreads();

        for (int t = 0; t <= 250; ++t) {
            const int rbA = (t + 1) & 1, wbA = t & 1;

            // publish g12(t-1): sum 4 wave partials, agent-scope store to ring
            if (t >= 1) {
                float v = PA[0][rbA][pub_pi] + PA[1][rbA][pub_pi] +
                          PA[2][rbA][pub_pi] + PA[3][rbA][pub_pi];
                __hip_atomic_store(&G12[((t - 1) & (RING - 1)) * 256 + j], v,
                                   __ATOMIC_RELAXED, __HIP_MEMORY_SCOPE_AGENT);
            }

            if (t < 250) {
                float g11 = PA[0][rbA][pidx_self] + PA[1][rbA][pidx_self] +
                            PA[2][rbA][pidx_self] + PA[3][rbA][pidx_self];
                float u = __uint_as_float((unsigned)ucur << 16);
                float h1 = u + b11p + g11;
                b1 = ro1 * b1 + omr1 * spk1;
                float B1 = 0.01f + 1.8f * b1;
                mem1 = mem1 * al1 + oma1 * h1 - B1 * spk1;
                spk1 = (mem1 - B1 > 0.f) ? 1.f : 0.f;

                unsigned long long m = __ballot(spk1 != 0.f);
                int n = __popcll(m);
                unsigned* L = listsA[wt];
                if (spk1 != 0.f) L[__popcll(m & below)] = (unsigned)j;
                L[n + lane] = 256u;                    // pads -> zero row
                asm volatile("s_waitcnt lgkmcnt(0)" ::: "memory");
                __builtin_amdgcn_wave_barrier();

                unsigned short unxt = Upb[H];
                Upb += H;

                v2f a[4];
                gatherB(L, n, C1b, (unsigned)lane * 8, a);

                float* pw = &PA[wt][wbA][10 * lane];
                *(v2f*)(pw + 0) = a[0];
                *(v2f*)(pw + 2) = a[1];
                *(v2f*)(pw + 4) = a[2];
                *(v2f*)(pw + 6) = a[3];
                ucur = unxt;
            }

            // ring overwrite throttle (B lags ~3; margin 13, refresh /8)
            if ((t & 7) == 0 && t > bd_c + 13) {
                while (true) {
                    bd_c = __hip_atomic_load(bdonep, __ATOMIC_RELAXED,
                                             __HIP_MEMORY_SCOPE_AGENT);
                    if (t <= bd_c + 13) break;
                    __builtin_amdgcn_s_sleep(8);
                }
            }

            // drain (publish stores + PA writes), barrier, then flag step t-1
            asm volatile("s_waitcnt vmcnt(0) lgkmcnt(0)" ::: "memory");
            __builtin_amdgcn_s_barrier();
            asm volatile("" ::: "memory");
            if (t >= 1 && tid == 0)
                __hip_atomic_store(progp, t, __ATOMIC_RELAXED,
                                   __HIP_MEMORY_SCOPE_AGENT);
        }
        return;
    }

    // ======================= B block =======================
    {
        unsigned* dst = (unsigned*)C2L;
        const unsigned* src = (const unsigned*)C2b;
        for (int i = tid; i < 193 * 144; i += 256)
            dst[i] = (i < 192 * 144) ? src[i] : 0u;
    }
    for (int i = tid; i < 4 * 2 * 432; i += 256) ((float*)PB)[i] = 0.f;

    float mem2 = mem2_0[bi * H + j];
    float al2 = __expf(-1.f / tau_m_h2[j]);
    float ro2 = __expf(-1.f / tau_adp_h2[j]);
    float oma2 = 1.f - al2, omr2 = 1.f - ro2;
    float bs2 = b12v[j] + b22v[j];
    float b2 = 0.01f, spk2 = 0.f;

    float memo = 0.f, alo = 0.f, omo = 0.f, bop = 0.f, acco = 0.f;
    const bool outl = (wt == 0 && lane < D_OUT);
    if (outl) {
        memo = memo_0[bi * D_OUT + lane];
        alo = __expf(-1.f / tau_m_o[lane]);
        omo = 1.f - alo;
        bop = bov[lane];
    }

    const unsigned mo = (unsigned)lane * 4;
    const unsigned ao = 256u + 2u * (unsigned)(lane & 15);
    const int qidx_j = QIDX(j);
    const int qidx_out = 384 + 6 * (lane >> 2) + (lane & 3);
    float g12c = 0.f, g12n = 0.f;
    __syncthreads();

    for (int tau = 0; tau <= 253; ++tau) {
        // prefetch g12(tau-2), used next window (latency hidden)
        if (tau >= 2 && tau <= 251) {
            const int want = tau - 1;
            while (__hip_atomic_load(progp, __ATOMIC_RELAXED,
                                     __HIP_MEMORY_SCOPE_AGENT) < want)
                __builtin_amdgcn_s_sleep(2);
            g12n = __hip_atomic_load(&G12[((tau - 2) & (RING - 1)) * 256 + j],
                                     __ATOMIC_RELAXED, __HIP_MEMORY_SCOPE_AGENT);
        }
        const int rsB = (tau + 1) & 1, wsB = tau & 1;

        // output chain for step s' = tau-4
        if (wt == 0 && tau >= 4) {
            float e = 0.f;
            if (lane < D_OUT) {
                float aO = PB[0][rsB][qidx_out] + PB[1][rsB][qidx_out] +
                           PB[2][rsB][qidx_out] + PB[3][rsB][qidx_out];
                memo = memo * alo + omo * (bop + aO);
                e = __expf(memo);
            }
            if (tau >= 15) {
                float s = e;
#pragma unroll
                for (int dd = 16; dd >= 1; dd >>= 1) s += __shfl_xor(s, dd, 32);
                if (lane < D_OUT) acco += __fdividef(e, s);
            }
        }

        // update2 for step s = tau-3 (g12 prefetched last window)
        if (tau >= 3 && tau <= 252) {
            float g22 = PB[0][rsB][qidx_j] + PB[1][rsB][qidx_j] +
                        PB[2][rsB][qidx_j] + PB[3][rsB][qidx_j];
            float h2 = bs2 + g22 + g12c;
            b2 = ro2 * b2 + omr2 * spk2;
            float B2 = 0.01f + 1.8f * b2;
            mem2 = mem2 * al2 + oma2 * h2 - B2 * spk2;
            spk2 = (mem2 - B2 > 0.f) ? 1.f : 0.f;

            unsigned long long m = __ballot(spk2 != 0.f);
            int n = __popcll(m);
            unsigned* L = listsB[wt];
            if (spk2 != 0.f) L[__popcll(m & below)] = (unsigned)j;
            L[n + lane] = (wt == 3) ? 256u : 192u;  // pads: global / LDS zero row
            asm volatile("s_waitcnt lgkmcnt(0)" ::: "memory");
            __builtin_amdgcn_wave_barrier();

            v2f g[2]; v2f aA;
            if (wt == 3) gather2(L, n, C2b, mo, ao, g, aA);
            else gather2(L, n, (const unsigned short*)C2L, mo, ao, g, aA);

            float* pw = &PB[wt][wsB][6 * lane];
            *(v2f*)(pw + 0) = g[0];
            *(v2f*)(pw + 2) = g[1];
            if (lane < 16) {
                float* pa = &PB[wt][wsB][384 + 6 * (lane >> 1) + 2 * (lane & 1)];
                *(v2f*)pa = aA;
            }
        }
        g12c = g12n;

        if (wt == 0 && lane == 0)
            __hip_atomic_store(bdonep, tau, __ATOMIC_RELAXED,
                               __HIP_MEMORY_SCOPE_AGENT);

        asm volatile("s_waitcnt lgkmcnt(0)" ::: "memory");
        __builtin_amdgcn_s_barrier();
        asm volatile("" ::: "memory");
    }

    if (outl) out[bi * D_OUT + lane] = acco;
}

// ---------------------------------------------------------------------------
extern "C" void kernel_launch(void* const* d_in, const int* in_sizes, int n_in,
                              void* d_out, int out_size, void* d_ws, size_t ws_size,
                              hipStream_t stream) {
    const float* x          = (const float*)d_in[0];
    const float* mem1_0     = (const float*)d_in[1];
    const float* mem2_0     = (const float*)d_in[2];
    const float* memo_0     = (const float*)d_in[3];
    const float* Wi1        = (const float*)d_in[4];
    const float* bi1        = (const float*)d_in[5];
    const float* W11        = (const float*)d_in[6];
    const float* b11        = (const float*)d_in[7];
    const float* W12        = (const float*)d_in[8];
    const float* b12        = (const float*)d_in[9];
    const float* W22        = (const float*)d_in[10];
    const float* b22        = (const float*)d_in[11];
    const float* Wo         = (const float*)d_in[12];
    const float* bo         = (const float*)d_in[13];
    const float* tau_adp_h1 = (const float*)d_in[14];
    const float* tau_adp_h2 = (const float*)d_in[15];
    const float* tau_m_h1   = (const float*)d_in[16];
    const float* tau_m_h2   = (const float*)d_in[17];
    const float* tau_m_o    = (const float*)d_in[18];

    unsigned short* Ub   = (unsigned short*)d_ws;       // [32001][256] bf16
    unsigned short* C1b  = Ub + (size_t)(BATCH * T + 1) * H;
    unsigned short* C2b  = C1b + N_C1;
    unsigned short* Wi1p = C2b + N_C2;
    float* G12           = (float*)(Wi1p + N_WP);       // [128][RING][256] f32
    int* prog            = (int*)(G12 + (size_t)BATCH * RING * 256);
    int* bdone           = prog + BATCH;

    hipMemsetAsync(prog, 0, 2 * BATCH * sizeof(int), stream);

    int prep_total = N_C1 + N_C2 + N_WP;
    prep_k<<<(prep_total + 255) / 256, 256, 0, stream>>>(
        Wi1, W11, W12, W22, Wo, Wi1p, C1b, C2b);

    gemm_u_k<<<(BATCH * T) / 64, 256, 0, stream>>>(x, Wi1p, bi1, Ub);

    recurrent_k<<<2 * BATCH, 256, 0, stream>>>(Ub, mem1_0, mem2_0, memo_0,
                                               b11, b12, b22, bo,
                                               tau_adp_h1, tau_adp_h2,
                                               tau_m_h1, tau_m_h2, tau_m_o,
                                               C1b, C2b, G12, prog, bdone,
                                               (float*)d_out);
}

// Round 12
// 611.007 us; speedup vs baseline: 1.0399x; 1.0399x over previous
//
#include <hip/hip_runtime.h>
#include <math.h>

#define BATCH 128
#define T 250
#define D_IN 700
#define H 256
#define D_OUT 20

typedef float v2f __attribute__((ext_vector_type(2)));
typedef __attribute__((ext_vector_type(8))) short bf16x8;
typedef __attribute__((ext_vector_type(4))) float f32x4;

static __device__ __forceinline__ unsigned short f2b(float f) {
    unsigned u = __float_as_uint(f);
    u += 0x7FFFu + ((u >> 16) & 1u);
    return (unsigned short)(u >> 16);
}

// Raw barrier: LDS ordering only (lgkmcnt). No vmcnt drain so global loads
// stay in flight across it.
static __device__ __forceinline__ void bar() {
    asm volatile("s_waitcnt lgkmcnt(0)" ::: "memory");
    __builtin_amdgcn_s_barrier();
    asm volatile("" ::: "memory");
}

// PA partial index (C1 cols, 8 f32/lane at stride 10) — R8-proven.
#define PIDX(c) (10 * ((c) >> 3) + ((c) & 7))
// PB partial index (compacted C2 cols, 4 f32/lane at stride 6) — R9/R10-proven.
#define QIDX(c) (6 * ((c) >> 2) + ((c) & 3))

// ---------------------------------------------------------------------------
// Workspace:
//   U     [32001][256] f32   (pad row: u-prefetch overrun at t=249)
//   C1f   [257][512] f32     p<256: W12T[k][p]; p>=256: W11T[k][p-256]
//   C2f   [257][288] f32     p<256: W22T[k][p]; p in [256,276): Wo[p-256][k]
//   Wi1p  [256][704] bf16    (MFMA K-pad)
//   row 256 of C1f/C2f all-zero (spike-list padding target)
//
// R12 = R10 structure (two-track skew, 8 waves, wave-own lists, 1 barrier
// per window, compacted C2, separate gemm_u; R11's cross-CU split reverted —
// 34MB of cross-XCD ring writes killed it) with ONE change: weight tables in
// f32. The window is instruction-issue-bound (R10's byte-shift null + instr
// accounting); bf16 unpack is 1.5 VALU/element vs f32's 0.75. Byte headroom
// exists: R7 sustained 150 B/cy/CU in this exact f32 regime.
// ---------------------------------------------------------------------------
#define N_C1 (257 * 512)
#define N_C2 (257 * 288)
#define N_WP (256 * 704)

__global__ void prep_k(const float* __restrict__ Wi1, const float* __restrict__ W11,
                       const float* __restrict__ W12, const float* __restrict__ W22,
                       const float* __restrict__ Wo,
                       unsigned short* __restrict__ Wi1p, float* __restrict__ C1,
                       float* __restrict__ C2) {
    int idx = blockIdx.x * 256 + threadIdx.x;
    if (idx < N_C1) {
        int k = idx >> 9, p = idx & 511;
        float v = 0.f;
        if (k < H) v = (p < 256) ? W12[p * H + k] : W11[(p - 256) * H + k];
        C1[idx] = v;
        return;
    }
    idx -= N_C1;
    if (idx < N_C2) {
        int k = idx / 288, p = idx - k * 288;
        float v = 0.f;
        if (k < H) {
            if (p < 256) v = W22[p * H + k];
            else if (p - 256 < D_OUT) v = Wo[(p - 256) * H + k];
        }
        C2[idx] = v;
        return;
    }
    idx -= N_C2;
    if (idx < N_WP) {
        int h = idx / 704, k = idx - h * 704;
        Wi1p[idx] = (k < D_IN) ? f2b(Wi1[h * D_IN + k]) : (unsigned short)0;
    }
}

// ---------------------------------------------------------------------------
// U = x @ Wi1^T + bi1 via MFMA 16x16x32 bf16 — R8-proven, unchanged (f32 U).
// ---------------------------------------------------------------------------
__global__ __launch_bounds__(256) void gemm_u_k(const float* __restrict__ x,
                                                const unsigned short* __restrict__ Wi1p,
                                                const float* __restrict__ bi1,
                                                float* __restrict__ U) {
    const int lane = threadIdx.x & 63;
    const int wv = threadIdx.x >> 6;
    const int quad = lane >> 4;
    const int nl = lane & 15;
    const int mbase = blockIdx.x * 64 + wv * 16;
    const int m = mbase + nl;

    f32x4 acc[16];
#pragma unroll
    for (int i = 0; i < 16; ++i) acc[i] = (f32x4)(0.f);

    float bias[16];
#pragma unroll
    for (int nt = 0; nt < 16; ++nt) bias[nt] = bi1[nt * 16 + nl];

    const float* xrow = x + (size_t)m * D_IN;
    const unsigned short* brow = Wi1p + nl * 704 + quad * 8;

    for (int k0 = 0; k0 < 704; k0 += 32) {
        int ka = k0 + quad * 8;
        int ka2 = (ka + 4 <= 696) ? ka + 4 : 696;
        float4 q0 = *(const float4*)(xrow + ka);
        float4 q1 = *(const float4*)(xrow + ka2);
        bf16x8 af;
        af[0] = (short)f2b(q0.x); af[1] = (short)f2b(q0.y);
        af[2] = (short)f2b(q0.z); af[3] = (short)f2b(q0.w);
        af[4] = (short)f2b(q1.x); af[5] = (short)f2b(q1.y);
        af[6] = (short)f2b(q1.z); af[7] = (short)f2b(q1.w);

        const unsigned short* bp = brow + k0;
        bf16x8 bf[16];
#pragma unroll
        for (int nt = 0; nt < 16; ++nt)
            bf[nt] = *(const bf16x8*)(bp + nt * 16 * 704);
#pragma unroll
        for (int nt = 0; nt < 16; ++nt)
            acc[nt] = __builtin_amdgcn_mfma_f32_16x16x32_bf16(af, bf[nt], acc[nt], 0, 0, 0);
    }

#pragma unroll
    for (int nt = 0; nt < 16; ++nt) {
#pragma unroll
        for (int r = 0; r < 4; ++r) {
            U[(size_t)(mbase + quad * 4 + r) * H + nt * 16 + nl] = acc[nt][r] + bias[nt];
        }
    }
}

// ---------------------------------------------------------------------------
// A-gather (C1 f32, 2KB rows, lane owns 8 cols via 2x dwordx4) — R7-proven.
// ---------------------------------------------------------------------------
static __device__ __forceinline__ void ld8f(const unsigned* __restrict__ L, int c,
                                            const float* __restrict__ Cb, unsigned l8,
                                            f32x4* ba, f32x4* bb) {
    uint4 ia = *(const uint4*)(L + c);
    uint4 ib = *(const uint4*)(L + c + 4);
    unsigned I[8] = {ia.x, ia.y, ia.z, ia.w, ib.x, ib.y, ib.z, ib.w};
#pragma unroll
    for (int j = 0; j < 8; ++j) {
        const float* p = Cb + ((unsigned)I[j] << 9) + l8;
        ba[j] = *(const f32x4*)p;
        bb[j] = *(const f32x4*)(p + 4);
    }
}

static __device__ __forceinline__ void acc8f(const f32x4* ba, const f32x4* bb,
                                             f32x4& A0, f32x4& A1) {
#pragma unroll
    for (int j = 0; j < 8; ++j) { A0 += ba[j]; A1 += bb[j]; }
}

static __device__ __forceinline__ void gather8(const unsigned* __restrict__ L, int n,
                                               const float* __restrict__ Cb, unsigned l8,
                                               f32x4& A0, f32x4& A1) {
    A0 = (f32x4)(0.f);
    A1 = (f32x4)(0.f);
    int nr = (n + 7) & ~7;
    if (nr == 0) return;
    f32x4 xa[8], xb[8], ya[8], yb[8];
    ld8f(L, 0, Cb, l8, xa, xb);
    if (nr == 8) { acc8f(xa, xb, A0, A1); return; }
    ld8f(L, 8, Cb, l8, ya, yb);
    int c = 16;
    for (; c + 16 <= nr; c += 16) {
        acc8f(xa, xb, A0, A1); ld8f(L, c, Cb, l8, xa, xb);
        acc8f(ya, yb, A0, A1); ld8f(L, c + 8, Cb, l8, ya, yb);
    }
    if (nr - c == 8) {
        acc8f(xa, xb, A0, A1); ld8f(L, c, Cb, l8, xa, xb);
        acc8f(ya, yb, A0, A1); acc8f(xa, xb, A0, A1);
    } else {
        acc8f(xa, xb, A0, A1); acc8f(ya, yb, A0, A1);
    }
}

// ---------------------------------------------------------------------------
// B-gather (C2 f32 compacted, 1152B rows): lane reads dwordx4 (4 main cols)
// + dwordx2 aux (2 of the 32 aO cols, 4x quad broadcast).
// ---------------------------------------------------------------------------
static __device__ __forceinline__ void ld8d(const unsigned* __restrict__ L, int c,
                                            const float* __restrict__ Cb,
                                            unsigned mo, unsigned ao,
                                            f32x4* m, v2f* av) {
    uint4 ia = *(const uint4*)(L + c);
    uint4 ib = *(const uint4*)(L + c + 4);
    unsigned I[8] = {ia.x, ia.y, ia.z, ia.w, ib.x, ib.y, ib.z, ib.w};
#pragma unroll
    for (int j = 0; j < 8; ++j) {
        const float* p = Cb + (unsigned)I[j] * 288u;
        m[j] = *(const f32x4*)(p + mo);
        av[j] = *(const v2f*)(p + ao);
    }
}

static __device__ __forceinline__ void acc8d(const f32x4* m, const v2f* av,
                                             f32x4& G, v2f& aA) {
#pragma unroll
    for (int j = 0; j < 8; ++j) { G += m[j]; aA += av[j]; }
}

static __device__ __forceinline__ void gather2f(const unsigned* __restrict__ L, int n,
                                                const float* __restrict__ Cb,
                                                unsigned mo, unsigned ao,
                                                f32x4& G, v2f& aA) {
    G = (f32x4)(0.f);
    aA = (v2f)(0.f);
    int nr = (n + 7) & ~7;
    if (nr == 0) return;
    f32x4 xm[8], ym[8]; v2f xa[8], ya[8];
    ld8d(L, 0, Cb, mo, ao, xm, xa);
    if (nr == 8) { acc8d(xm, xa, G, aA); return; }
    ld8d(L, 8, Cb, mo, ao, ym, ya);
    int c = 16;
    for (; c + 16 <= nr; c += 16) {
        acc8d(xm, xa, G, aA); ld8d(L, c, Cb, mo, ao, xm, xa);
        acc8d(ym, ya, G, aA); ld8d(L, c + 8, Cb, mo, ao, ym, ya);
    }
    if (nr - c == 8) {
        acc8d(xm, xa, G, aA); ld8d(L, c, Cb, mo, ao, xm, xa);
        acc8d(ym, ya, G, aA); acc8d(xm, xa, G, aA);
    } else {
        acc8d(xm, xa, G, aA); acc8d(ym, ya, G, aA);
    }
}

// ---------------------------------------------------------------------------
// Recurrent: one BLOCK (8 waves, 512 threads) per batch element.
// Waves 0-3 = track A (layer 1, step t), waves 4-7 = track B (layer 2, t-1;
// wave 4 also output chain at t-2). One barrier per window. R10 skew logic.
// ---------------------------------------------------------------------------
__global__ __launch_bounds__(512, 1) void recurrent_k(
    const float* __restrict__ U,
    const float* __restrict__ mem1_0, const float* __restrict__ mem2_0,
    const float* __restrict__ memo_0,
    const float* __restrict__ b11v, const float* __restrict__ b12v,
    const float* __restrict__ b22v, const float* __restrict__ bov,
    const float* __restrict__ tau_adp_h1, const float* __restrict__ tau_adp_h2,
    const float* __restrict__ tau_m_h1, const float* __restrict__ tau_m_h2,
    const float* __restrict__ tau_m_o,
    const float* __restrict__ C1f, const float* __restrict__ C2f,
    float* __restrict__ out)
{
    const int tid = threadIdx.x;
    const int lane = tid & 63;
    const int w = tid >> 6;           // 0..7
    const bool trackA = (w < 4);
    const int wt = w & 3;             // wave-in-track
    const int bi = blockIdx.x;
    const int j = wt * 64 + lane;     // owned neuron (both layers)
    const unsigned l8 = (unsigned)lane * 8;          // C1 f32 offset (8 cols)
    const unsigned mo = (unsigned)lane * 4;          // C2 main f32 offset
    const unsigned ao = 256u + 2u * (unsigned)(lane & 15);  // C2 aux f32 offset

    __shared__ float PA[4][2][640];                    // 20480 B
    __shared__ float PB[4][2][432];                    // 13824 B
    __shared__ __align__(16) unsigned lists[8][128];   // 4096 B

    for (int i = tid; i < 4 * 2 * 640; i += 512) ((float*)PA)[i] = 0.f;
    for (int i = tid; i < 4 * 2 * 432; i += 512) ((float*)PB)[i] = 0.f;

    // ---- track A state (layer 1) ----
    float mem1 = 0.f, b1 = 0.01f, spk1 = 0.f;
    float al1 = 0.f, ro1 = 0.f, oma1 = 0.f, omr1 = 0.f, b11p = 0.f;
    if (trackA) {
        mem1 = mem1_0[bi * H + j];
        al1 = __expf(-1.f / tau_m_h1[j]);
        ro1 = __expf(-1.f / tau_adp_h1[j]);
        oma1 = 1.f - al1; omr1 = 1.f - ro1;
        b11p = b11v[j];
    }

    // ---- track B state (layer 2) ----
    float mem2 = 0.f, b2 = 0.01f, spk2 = 0.f;
    float al2 = 0.f, ro2 = 0.f, oma2 = 0.f, omr2 = 0.f, bs2 = 0.f;
    if (!trackA) {
        mem2 = mem2_0[bi * H + j];
        al2 = __expf(-1.f / tau_m_h2[j]);
        ro2 = __expf(-1.f / tau_adp_h2[j]);
        oma2 = 1.f - al2; omr2 = 1.f - ro2;
        bs2 = b12v[j] + b22v[j];
    }

    // ---- wave-4 output state ----
    float memo = 0.f, alo = 0.f, omo = 0.f, bop = 0.f, acco = 0.f;
    const bool outl = (w == 4 && lane < D_OUT);
    if (outl) {
        memo = memo_0[bi * D_OUT + lane];
        alo = __expf(-1.f / tau_m_o[lane]);
        omo = 1.f - alo;
        bop = bov[lane];
    }

    const float* Up = U + (size_t)bi * T * H + j;
    float u_cur = trackA ? *Up : 0.f;
    float u_nxt = 0.f;
    const unsigned long long below = (1ull << lane) - 1ull;

    const int pidx_self = 320 + PIDX(j);    // PIDX(256+j) in PA (g11)
    const int pidx_j = PIDX(j);             // g12 in PA
    const int qidx_j = QIDX(j);             // g22 in PB
    const int qidx_out = 384 + 6 * (lane >> 2) + (lane & 3);  // QIDX(256+lane)

    __syncthreads();

    for (int t = 0; t < 252; ++t) {
        const int rbA = (t + 1) & 1;
        const int wbA = t & 1;
        const int rsB = (t + 1) & 1;     // PB slot written at t-1, read here
        const int wsB = t & 1;

        if (trackA && t < 250) {
            float g11 = PA[0][rbA][pidx_self] + PA[1][rbA][pidx_self] +
                        PA[2][rbA][pidx_self] + PA[3][rbA][pidx_self];
            float h1 = u_cur + b11p + g11;
            b1 = ro1 * b1 + omr1 * spk1;
            float B1 = 0.01f + 1.8f * b1;
            mem1 = mem1 * al1 + oma1 * h1 - B1 * spk1;
            spk1 = (mem1 - B1 > 0.f) ? 1.f : 0.f;

            unsigned long long m = __ballot(spk1 != 0.f);
            int n = __popcll(m);
            unsigned* L = lists[w];
            if (spk1 != 0.f) L[__popcll(m & below)] = (unsigned)j;
            L[n + lane] = 256u;          // pads -> all-zero row
            asm volatile("s_waitcnt lgkmcnt(0)" ::: "memory");
            __builtin_amdgcn_wave_barrier();

            u_nxt = Up[H];               // pad row covers t=249 overrun
            Up += H;

            f32x4 A0, A1;
            gather8(L, n, C1f, l8, A0, A1);

            float* pw = &PA[wt][wbA][10 * lane];
            const v2f* ap = (const v2f*)&A0;
            const v2f* bp = (const v2f*)&A1;
            *(v2f*)(pw + 0) = ap[0];
            *(v2f*)(pw + 2) = ap[1];
            *(v2f*)(pw + 4) = bp[0];
            *(v2f*)(pw + 6) = bp[1];
            u_cur = u_nxt;
        }

        if (w == 4 && t >= 2) {
            // output chain for step s = t-2
            float e = 0.f;
            if (lane < D_OUT) {
                float aO = PB[0][rsB][qidx_out] + PB[1][rsB][qidx_out] +
                           PB[2][rsB][qidx_out] + PB[3][rsB][qidx_out];
                memo = memo * alo + omo * (bop + aO);
                e = __expf(memo);
            }
            if (t >= 13) {
                float s = e;
#pragma unroll
                for (int dd = 16; dd >= 1; dd >>= 1) s += __shfl_xor(s, dd, 32);
                if (lane < D_OUT) acco += __fdividef(e, s);
            }
        }

        if (!trackA && t >= 1 && t < 251) {
            // update2(t-1): g12 from G1(t-1), g22 from G2(t-2)
            float g12 = PA[0][rbA][pidx_j] + PA[1][rbA][pidx_j] +
                        PA[2][rbA][pidx_j] + PA[3][rbA][pidx_j];
            float g22 = PB[0][rsB][qidx_j] + PB[1][rsB][qidx_j] +
                        PB[2][rsB][qidx_j] + PB[3][rsB][qidx_j];
            float h2 = bs2 + g22 + g12;
            b2 = ro2 * b2 + omr2 * spk2;
            float B2 = 0.01f + 1.8f * b2;
            mem2 = mem2 * al2 + oma2 * h2 - B2 * spk2;
            spk2 = (mem2 - B2 > 0.f) ? 1.f : 0.f;

            unsigned long long m = __ballot(spk2 != 0.f);
            int n = __popcll(m);
            unsigned* L = lists[w];
            if (spk2 != 0.f) L[__popcll(m & below)] = (unsigned)j;
            L[n + lane] = 256u;          // pads -> all-zero row
            asm volatile("s_waitcnt lgkmcnt(0)" ::: "memory");
            __builtin_amdgcn_wave_barrier();

            f32x4 G; v2f aA;
            gather2f(L, n, C2f, mo, ao, G, aA);

            float* pw = &PB[wt][wsB][6 * lane];
            const v2f* gp = (const v2f*)&G;
            *(v2f*)(pw + 0) = gp[0];
            *(v2f*)(pw + 2) = gp[1];
            if (lane < 16) {
                float* pa = &PB[wt][wsB][384 + 6 * (lane >> 1) + 2 * (lane & 1)];
                *(v2f*)pa = aA;
            }
        }

        bar();   // single barrier per window
    }

    if (outl) out[bi * D_OUT + lane] = acco;
}

// ---------------------------------------------------------------------------
extern "C" void kernel_launch(void* const* d_in, const int* in_sizes, int n_in,
                              void* d_out, int out_size, void* d_ws, size_t ws_size,
                              hipStream_t stream) {
    const float* x          = (const float*)d_in[0];
    const float* mem1_0     = (const float*)d_in[1];
    const float* mem2_0     = (const float*)d_in[2];
    const float* memo_0     = (const float*)d_in[3];
    const float* Wi1        = (const float*)d_in[4];
    const float* bi1        = (const float*)d_in[5];
    const float* W11        = (const float*)d_in[6];
    const float* b11        = (const float*)d_in[7];
    const float* W12        = (const float*)d_in[8];
    const float* b12        = (const float*)d_in[9];
    const float* W22        = (const float*)d_in[10];
    const float* b22        = (const float*)d_in[11];
    const float* Wo         = (const float*)d_in[12];
    const float* bo         = (const float*)d_in[13];
    const float* tau_adp_h1 = (const float*)d_in[14];
    const float* tau_adp_h2 = (const float*)d_in[15];
    const float* tau_m_h1   = (const float*)d_in[16];
    const float* tau_m_h2   = (const float*)d_in[17];
    const float* tau_m_o    = (const float*)d_in[18];

    float* U = (float*)d_ws;                            // [32001][256] f32
    float* C1f = U + ((size_t)BATCH * T + 1) * H;       // [257][512] f32
    float* C2f = C1f + N_C1;                            // [257][288] f32
    unsigned short* Wi1p = (unsigned short*)(C2f + N_C2); // [256][704] bf16

    int prep_total = N_C1 + N_C2 + N_WP;
    prep_k<<<(prep_total + 255) / 256, 256, 0, stream>>>(
        Wi1, W11, W12, W22, Wo, Wi1p, C1f, C2f);

    gemm_u_k<<<(BATCH * T) / 64, 256, 0, stream>>>(x, Wi1p, bi1, U);

    recurrent_k<<<BATCH, 512, 0, stream>>>(U, mem1_0, mem2_0, memo_0,
                                           b11, b12, b22, bo,
                                           tau_adp_h1, tau_adp_h2,
                                           tau_m_h1, tau_m_h2, tau_m_o,
                                           C1f, C2f, (float*)d_out);
}

// Round 13
// 400.115 us; speedup vs baseline: 1.5881x; 1.5271x over previous
//
#include <hip/hip_runtime.h>
#include <math.h>

#define BATCH 128
#define T 250
#define D_IN 700
#define H 256
#define D_OUT 20

typedef float v2f __attribute__((ext_vector_type(2)));
typedef __attribute__((ext_vector_type(8))) short bf16x8;
typedef __attribute__((ext_vector_type(4))) float f32x4;
typedef __attribute__((ext_vector_type(4))) unsigned u32x4;

static __device__ __forceinline__ unsigned short f2b(float f) {
    unsigned u = __float_as_uint(f);
    u += 0x7FFFu + ((u >> 16) & 1u);
    return (unsigned short)(u >> 16);
}

// Raw barrier: LDS ordering only (lgkmcnt). No vmcnt drain so global loads
// stay in flight across it.
static __device__ __forceinline__ void bar() {
    asm volatile("s_waitcnt lgkmcnt(0)" ::: "memory");
    __builtin_amdgcn_s_barrier();
    asm volatile("" ::: "memory");
}

// PA partial index (C1 cols, 8 f32/lane at stride 10) — R8-proven.
#define PIDX(c) (10 * ((c) >> 3) + ((c) & 7))
// PB partial index (compacted C2 cols, 4 f32/lane at stride 6) — R9/R10-proven.
#define QIDX(c) (6 * ((c) >> 2) + ((c) & 3))

// ---------------------------------------------------------------------------
// Workspace:
//   U     [32001][256] f32   (pad row: u-prefetch overrun at t=249)
//   C1b   [257][512] bf16    p<256: W12T[k][p]; p>=256: W11T[k][p-256]
//   C2b   [257][288] bf16    p<256: W22T[k][p]; p in [256,276): Wo[p-256][k]
//   Wi1p  [256][704] bf16    (MFMA K-pad)
//   row 256 of C1b/C2b all-zero (spike-list padding target)
//
// R13 = the one untested ablation cell: R8's proven base (bf16 tables —
// REQUIRED: f32 buffers blow the VGPR budget, R12's 128-reg collapse —
// two-track skew, 8 waves, wave-own lists, 1 barrier/window, separate
// gemm_u) + C2 compaction ONLY (R9/R10-proven correct; 576B rows kill the
// 44% structural-zero bytes + 25% of B-track unpack VALU). No LDS staging
// (R10: null), no JIT-U (R9: regression), no f32 (R12: regression).
// ---------------------------------------------------------------------------
#define N_C1 (257 * 512)
#define N_C2 (257 * 288)
#define N_WP (256 * 704)

__global__ void prep_k(const float* __restrict__ Wi1, const float* __restrict__ W11,
                       const float* __restrict__ W12, const float* __restrict__ W22,
                       const float* __restrict__ Wo,
                       unsigned short* __restrict__ Wi1p, unsigned short* __restrict__ C1,
                       unsigned short* __restrict__ C2) {
    int idx = blockIdx.x * 256 + threadIdx.x;
    if (idx < N_C1) {
        int k = idx >> 9, p = idx & 511;
        float v = 0.f;
        if (k < H) v = (p < 256) ? W12[p * H + k] : W11[(p - 256) * H + k];
        C1[idx] = f2b(v);
        return;
    }
    idx -= N_C1;
    if (idx < N_C2) {
        int k = idx / 288, p = idx - k * 288;
        float v = 0.f;
        if (k < H) {
            if (p < 256) v = W22[p * H + k];
            else if (p - 256 < D_OUT) v = Wo[(p - 256) * H + k];
        }
        C2[idx] = f2b(v);
        return;
    }
    idx -= N_C2;
    if (idx < N_WP) {
        int h = idx / 704, k = idx - h * 704;
        Wi1p[idx] = (k < D_IN) ? f2b(Wi1[h * D_IN + k]) : (unsigned short)0;
    }
}

// ---------------------------------------------------------------------------
// U = x @ Wi1^T + bi1 via MFMA 16x16x32 bf16 — R8-proven, unchanged.
// ---------------------------------------------------------------------------
__global__ __launch_bounds__(256) void gemm_u_k(const float* __restrict__ x,
                                                const unsigned short* __restrict__ Wi1p,
                                                const float* __restrict__ bi1,
                                                float* __restrict__ U) {
    const int lane = threadIdx.x & 63;
    const int wv = threadIdx.x >> 6;
    const int quad = lane >> 4;
    const int nl = lane & 15;
    const int mbase = blockIdx.x * 64 + wv * 16;
    const int m = mbase + nl;

    f32x4 acc[16];
#pragma unroll
    for (int i = 0; i < 16; ++i) acc[i] = (f32x4)(0.f);

    float bias[16];
#pragma unroll
    for (int nt = 0; nt < 16; ++nt) bias[nt] = bi1[nt * 16 + nl];

    const float* xrow = x + (size_t)m * D_IN;
    const unsigned short* brow = Wi1p + nl * 704 + quad * 8;

    for (int k0 = 0; k0 < 704; k0 += 32) {
        int ka = k0 + quad * 8;
        int ka2 = (ka + 4 <= 696) ? ka + 4 : 696;
        float4 q0 = *(const float4*)(xrow + ka);
        float4 q1 = *(const float4*)(xrow + ka2);
        bf16x8 af;
        af[0] = (short)f2b(q0.x); af[1] = (short)f2b(q0.y);
        af[2] = (short)f2b(q0.z); af[3] = (short)f2b(q0.w);
        af[4] = (short)f2b(q1.x); af[5] = (short)f2b(q1.y);
        af[6] = (short)f2b(q1.z); af[7] = (short)f2b(q1.w);

        const unsigned short* bp = brow + k0;
        bf16x8 bf[16];
#pragma unroll
        for (int nt = 0; nt < 16; ++nt)
            bf[nt] = *(const bf16x8*)(bp + nt * 16 * 704);
#pragma unroll
        for (int nt = 0; nt < 16; ++nt)
            acc[nt] = __builtin_amdgcn_mfma_f32_16x16x32_bf16(af, bf[nt], acc[nt], 0, 0, 0);
    }

#pragma unroll
    for (int nt = 0; nt < 16; ++nt) {
#pragma unroll
        for (int r = 0; r < 4; ++r) {
            U[(size_t)(mbase + quad * 4 + r) * H + nt * 16 + nl] = acc[nt][r] + bias[nt];
        }
    }
}

// ---------------------------------------------------------------------------
// A-gather (C1 bf16, 1KB rows, lane owns 8 cols via 1 dwordx4) — R8-proven.
// ---------------------------------------------------------------------------
static __device__ __forceinline__ void ld8b(const unsigned* __restrict__ L, int c,
                                            const unsigned short* __restrict__ Cb,
                                            unsigned l8, u32x4* b) {
    uint4 ia = *(const uint4*)(L + c);
    uint4 ib = *(const uint4*)(L + c + 4);
    unsigned I[8] = {ia.x, ia.y, ia.z, ia.w, ib.x, ib.y, ib.z, ib.w};
#pragma unroll
    for (int jj = 0; jj < 8; ++jj)
        b[jj] = *(const u32x4*)(Cb + ((unsigned)I[jj] << 9) + l8);
}

static __device__ __forceinline__ void acc8b(const u32x4* b, v2f* a) {
#pragma unroll
    for (int jj = 0; jj < 8; ++jj) {
#pragma unroll
        for (int q = 0; q < 4; ++q) {
            unsigned u = b[jj][q];
            v2f t;
            t.x = __uint_as_float(u << 16);
            t.y = __uint_as_float(u & 0xffff0000u);
            a[q] += t;
        }
    }
}

static __device__ __forceinline__ void gatherB(const unsigned* __restrict__ L, int n,
                                               const unsigned short* __restrict__ Cb,
                                               unsigned l8, v2f* a) {
    a[0] = (v2f)(0.f); a[1] = (v2f)(0.f); a[2] = (v2f)(0.f); a[3] = (v2f)(0.f);
    int nr = (n + 7) & ~7;
    if (nr == 0) return;
    u32x4 x[8], y[8];
    ld8b(L, 0, Cb, l8, x);
    if (nr == 8) { acc8b(x, a); return; }
    ld8b(L, 8, Cb, l8, y);
    int c = 16;
    for (; c + 16 <= nr; c += 16) {
        acc8b(x, a); ld8b(L, c, Cb, l8, x);
        acc8b(y, a); ld8b(L, c + 8, Cb, l8, y);
    }
    if (nr - c == 8) {
        acc8b(x, a); ld8b(L, c, Cb, l8, x);
        acc8b(y, a); acc8b(x, a);
    } else {
        acc8b(x, a); acc8b(y, a);
    }
}

// ---------------------------------------------------------------------------
// B-gather (C2 bf16 compacted, 576B rows): lane reads uint2 (its 4 g22 cols)
// + aux dword (2 of the 32 aO cols, 4x quad broadcast) — R9/R10-proven.
// ---------------------------------------------------------------------------
static __device__ __forceinline__ void ld8c(const unsigned* __restrict__ L, int c,
                                            const unsigned short* __restrict__ Cb,
                                            unsigned mo, unsigned ao,
                                            uint2* m, unsigned* av) {
    uint4 ia = *(const uint4*)(L + c);
    uint4 ib = *(const uint4*)(L + c + 4);
    unsigned I[8] = {ia.x, ia.y, ia.z, ia.w, ib.x, ib.y, ib.z, ib.w};
#pragma unroll
    for (int jj = 0; jj < 8; ++jj) {
        const unsigned short* p = Cb + (unsigned)I[jj] * 288u;
        m[jj] = *(const uint2*)(p + mo);
        av[jj] = *(const unsigned*)(p + ao);
    }
}

static __device__ __forceinline__ void acc8c(const uint2* m, const unsigned* av,
                                             v2f* g, v2f& aA) {
#pragma unroll
    for (int jj = 0; jj < 8; ++jj) {
        unsigned u0 = m[jj].x, u1 = m[jj].y, uA = av[jj];
        v2f t0, t1, tA;
        t0.x = __uint_as_float(u0 << 16); t0.y = __uint_as_float(u0 & 0xffff0000u);
        t1.x = __uint_as_float(u1 << 16); t1.y = __uint_as_float(u1 & 0xffff0000u);
        tA.x = __uint_as_float(uA << 16); tA.y = __uint_as_float(uA & 0xffff0000u);
        g[0] += t0; g[1] += t1; aA += tA;
    }
}

static __device__ __forceinline__ void gather2(const unsigned* __restrict__ L, int n,
                                               const unsigned short* __restrict__ Cb,
                                               unsigned mo, unsigned ao,
                                               v2f* g, v2f& aA) {
    g[0] = (v2f)(0.f); g[1] = (v2f)(0.f); aA = (v2f)(0.f);
    int nr = (n + 7) & ~7;
    if (nr == 0) return;
    uint2 xm[8], ym[8]; unsigned xa[8], ya[8];
    ld8c(L, 0, Cb, mo, ao, xm, xa);
    if (nr == 8) { acc8c(xm, xa, g, aA); return; }
    ld8c(L, 8, Cb, mo, ao, ym, ya);
    int c = 16;
    for (; c + 16 <= nr; c += 16) {
        acc8c(xm, xa, g, aA); ld8c(L, c, Cb, mo, ao, xm, xa);
        acc8c(ym, ya, g, aA); ld8c(L, c + 8, Cb, mo, ao, ym, ya);
    }
    if (nr - c == 8) {
        acc8c(xm, xa, g, aA); ld8c(L, c, Cb, mo, ao, xm, xa);
        acc8c(ym, ya, g, aA); acc8c(xm, xa, g, aA);
    } else {
        acc8c(xm, xa, g, aA); acc8c(ym, ya, g, aA);
    }
}

// ---------------------------------------------------------------------------
// Recurrent: one BLOCK (8 waves, 512 threads) per batch element.
// Waves 0-3 = track A (layer 1, step t), waves 4-7 = track B (layer 2, t-1;
// wave 4 also output chain at t-2). One barrier per window. PB 2-slot
// (R10-proven lifetime: write@t -> read@t+1).
// ---------------------------------------------------------------------------
__global__ __launch_bounds__(512, 1) void recurrent_k(
    const float* __restrict__ U,
    const float* __restrict__ mem1_0, const float* __restrict__ mem2_0,
    const float* __restrict__ memo_0,
    const float* __restrict__ b11v, const float* __restrict__ b12v,
    const float* __restrict__ b22v, const float* __restrict__ bov,
    const float* __restrict__ tau_adp_h1, const float* __restrict__ tau_adp_h2,
    const float* __restrict__ tau_m_h1, const float* __restrict__ tau_m_h2,
    const float* __restrict__ tau_m_o,
    const unsigned short* __restrict__ C1b, const unsigned short* __restrict__ C2b,
    float* __restrict__ out)
{
    const int tid = threadIdx.x;
    const int lane = tid & 63;
    const int w = tid >> 6;           // 0..7
    const bool trackA = (w < 4);
    const int wt = w & 3;             // wave-in-track
    const int bi = blockIdx.x;
    const int j = wt * 64 + lane;     // owned neuron (both layers)
    const unsigned l8 = (unsigned)lane * 8;          // C1 shorts offset (8 cols)
    const unsigned mo = (unsigned)lane * 4;          // C2 main shorts offset
    const unsigned ao = 256u + 2u * (unsigned)(lane & 15);  // C2 aux shorts offset

    __shared__ float PA[4][2][640];                    // 20480 B
    __shared__ float PB[4][2][432];                    // 13824 B
    __shared__ __align__(16) unsigned lists[8][128];   // 4096 B

    for (int i = tid; i < 4 * 2 * 640; i += 512) ((float*)PA)[i] = 0.f;
    for (int i = tid; i < 4 * 2 * 432; i += 512) ((float*)PB)[i] = 0.f;

    // ---- track A state (layer 1) ----
    float mem1 = 0.f, b1 = 0.01f, spk1 = 0.f;
    float al1 = 0.f, ro1 = 0.f, oma1 = 0.f, omr1 = 0.f, b11p = 0.f;
    if (trackA) {
        mem1 = mem1_0[bi * H + j];
        al1 = __expf(-1.f / tau_m_h1[j]);
        ro1 = __expf(-1.f / tau_adp_h1[j]);
        oma1 = 1.f - al1; omr1 = 1.f - ro1;
        b11p = b11v[j];
    }

    // ---- track B state (layer 2) ----
    float mem2 = 0.f, b2 = 0.01f, spk2 = 0.f;
    float al2 = 0.f, ro2 = 0.f, oma2 = 0.f, omr2 = 0.f, bs2 = 0.f;
    if (!trackA) {
        mem2 = mem2_0[bi * H + j];
        al2 = __expf(-1.f / tau_m_h2[j]);
        ro2 = __expf(-1.f / tau_adp_h2[j]);
        oma2 = 1.f - al2; omr2 = 1.f - ro2;
        bs2 = b12v[j] + b22v[j];
    }

    // ---- wave-4 output state ----
    float memo = 0.f, alo = 0.f, omo = 0.f, bop = 0.f, acco = 0.f;
    const bool outl = (w == 4 && lane < D_OUT);
    if (outl) {
        memo = memo_0[bi * D_OUT + lane];
        alo = __expf(-1.f / tau_m_o[lane]);
        omo = 1.f - alo;
        bop = bov[lane];
    }

    const float* Up = U + (size_t)bi * T * H + j;
    float u_cur = trackA ? *Up : 0.f;
    float u_nxt = 0.f;
    const unsigned long long below = (1ull << lane) - 1ull;

    const int pidx_self = 320 + PIDX(j);    // PIDX(256+j) in PA (g11)
    const int pidx_j = PIDX(j);             // g12 in PA
    const int qidx_j = QIDX(j);             // g22 in PB
    const int qidx_out = 384 + 6 * (lane >> 2) + (lane & 3);  // QIDX(256+lane)

    __syncthreads();

    for (int t = 0; t < 252; ++t) {
        const int rbA = (t + 1) & 1;
        const int wbA = t & 1;
        const int rsB = (t + 1) & 1;     // PB slot written at t-1, read here
        const int wsB = t & 1;

        if (trackA && t < 250) {
            float g11 = PA[0][rbA][pidx_self] + PA[1][rbA][pidx_self] +
                        PA[2][rbA][pidx_self] + PA[3][rbA][pidx_self];
            float h1 = u_cur + b11p + g11;
            b1 = ro1 * b1 + omr1 * spk1;
            float B1 = 0.01f + 1.8f * b1;
            mem1 = mem1 * al1 + oma1 * h1 - B1 * spk1;
            spk1 = (mem1 - B1 > 0.f) ? 1.f : 0.f;

            unsigned long long m = __ballot(spk1 != 0.f);
            int n = __popcll(m);
            unsigned* L = lists[w];
            if (spk1 != 0.f) L[__popcll(m & below)] = (unsigned)j;
            L[n + lane] = 256u;          // pads -> all-zero row
            asm volatile("s_waitcnt lgkmcnt(0)" ::: "memory");
            __builtin_amdgcn_wave_barrier();

            u_nxt = Up[H];               // pad row covers t=249 overrun
            Up += H;

            v2f a[4];
            gatherB(L, n, C1b, l8, a);

            float* pw = &PA[wt][wbA][10 * lane];
            *(v2f*)(pw + 0) = a[0];
            *(v2f*)(pw + 2) = a[1];
            *(v2f*)(pw + 4) = a[2];
            *(v2f*)(pw + 6) = a[3];
            u_cur = u_nxt;
        }

        if (w == 4 && t >= 2) {
            // output chain for step s = t-2
            float e = 0.f;
            if (lane < D_OUT) {
                float aO = PB[0][rsB][qidx_out] + PB[1][rsB][qidx_out] +
                           PB[2][rsB][qidx_out] + PB[3][rsB][qidx_out];
                memo = memo * alo + omo * (bop + aO);
                e = __expf(memo);
            }
            if (t >= 13) {
                float s = e;
#pragma unroll
                for (int dd = 16; dd >= 1; dd >>= 1) s += __shfl_xor(s, dd, 32);
                if (lane < D_OUT) acco += __fdividef(e, s);
            }
        }

        if (!trackA && t >= 1 && t < 251) {
            // update2(t-1): g12 from G1(t-1), g22 from G2(t-2)
            float g12 = PA[0][rbA][pidx_j] + PA[1][rbA][pidx_j] +
                        PA[2][rbA][pidx_j] + PA[3][rbA][pidx_j];
            float g22 = PB[0][rsB][qidx_j] + PB[1][rsB][qidx_j] +
                        PB[2][rsB][qidx_j] + PB[3][rsB][qidx_j];
            float h2 = bs2 + g22 + g12;
            b2 = ro2 * b2 + omr2 * spk2;
            float B2 = 0.01f + 1.8f * b2;
            mem2 = mem2 * al2 + oma2 * h2 - B2 * spk2;
            spk2 = (mem2 - B2 > 0.f) ? 1.f : 0.f;

            unsigned long long m = __ballot(spk2 != 0.f);
            int n = __popcll(m);
            unsigned* L = lists[w];
            if (spk2 != 0.f) L[__popcll(m & below)] = (unsigned)j;
            L[n + lane] = 256u;          // pads -> all-zero row
            asm volatile("s_waitcnt lgkmcnt(0)" ::: "memory");
            __builtin_amdgcn_wave_barrier();

            v2f g[2]; v2f aA;
            gather2(L, n, C2b, mo, ao, g, aA);

            float* pw = &PB[wt][wsB][6 * lane];
            *(v2f*)(pw + 0) = g[0];
            *(v2f*)(pw + 2) = g[1];
            if (lane < 16) {
                float* pa = &PB[wt][wsB][384 + 6 * (lane >> 1) + 2 * (lane & 1)];
                *(v2f*)pa = aA;
            }
        }

        bar();   // single barrier per window
    }

    if (outl) out[bi * D_OUT + lane] = acco;
}

// ---------------------------------------------------------------------------
extern "C" void kernel_launch(void* const* d_in, const int* in_sizes, int n_in,
                              void* d_out, int out_size, void* d_ws, size_t ws_size,
                              hipStream_t stream) {
    const float* x          = (const float*)d_in[0];
    const float* mem1_0     = (const float*)d_in[1];
    const float* mem2_0     = (const float*)d_in[2];
    const float* memo_0     = (const float*)d_in[3];
    const float* Wi1        = (const float*)d_in[4];
    const float* bi1        = (const float*)d_in[5];
    const float* W11        = (const float*)d_in[6];
    const float* b11        = (const float*)d_in[7];
    const float* W12        = (const float*)d_in[8];
    const float* b12        = (const float*)d_in[9];
    const float* W22        = (const float*)d_in[10];
    const float* b22        = (const float*)d_in[11];
    const float* Wo         = (const float*)d_in[12];
    const float* bo         = (const float*)d_in[13];
    const float* tau_adp_h1 = (const float*)d_in[14];
    const float* tau_adp_h2 = (const float*)d_in[15];
    const float* tau_m_h1   = (const float*)d_in[16];
    const float* tau_m_h2   = (const float*)d_in[17];
    const float* tau_m_o    = (const float*)d_in[18];

    float* U = (float*)d_ws;                            // [32001][256] f32
    unsigned short* C1b  = (unsigned short*)(U + ((size_t)BATCH * T + 1) * H);
    unsigned short* C2b  = C1b + N_C1;                  // [257][288] bf16
    unsigned short* Wi1p = C2b + N_C2;                  // [256][704] bf16

    int prep_total = N_C1 + N_C2 + N_WP;
    prep_k<<<(prep_total + 255) / 256, 256, 0, stream>>>(
        Wi1, W11, W12, W22, Wo, Wi1p, C1b, C2b);

    gemm_u_k<<<(BATCH * T) / 64, 256, 0, stream>>>(x, Wi1p, bi1, U);

    recurrent_k<<<BATCH, 512, 0, stream>>>(U, mem1_0, mem2_0, memo_0,
                                           b11, b12, b22, bo,
                                           tau_adp_h1, tau_adp_h2,
                                           tau_m_h1, tau_m_h2, tau_m_o,
                                           C1b, C2b, (float*)d_out);
}

// Round 14
// 385.219 us; speedup vs baseline: 1.6495x; 1.0387x over previous
//
#include <hip/hip_runtime.h>
#include <math.h>

#define BATCH 128
#define T 250
#define D_IN 700
#define H 256
#define D_OUT 20

typedef float v2f __attribute__((ext_vector_type(2)));
typedef __attribute__((ext_vector_type(8))) short bf16x8;
typedef __attribute__((ext_vector_type(4))) float f32x4;
typedef __attribute__((ext_vector_type(4))) unsigned u32x4;

static __device__ __forceinline__ unsigned short f2b(float f) {
    unsigned u = __float_as_uint(f);
    u += 0x7FFFu + ((u >> 16) & 1u);
    return (unsigned short)(u >> 16);
}

// Raw barrier: LDS ordering only (lgkmcnt). No vmcnt drain so global loads
// (u_nxt prefetch, gather pipeline) stay in flight across it.
static __device__ __forceinline__ void bar() {
    asm volatile("s_waitcnt lgkmcnt(0)" ::: "memory");
    __builtin_amdgcn_s_barrier();
    asm volatile("" ::: "memory");
}

// Padded LDS partial index: 8 cols -> stride 10 (2-way max on b64 writes).
#define PIDX(c) (10 * ((c) >> 3) + ((c) & 7))

// ---------------------------------------------------------------------------
// Workspace layout (R8 champion, restored verbatim):
//   U     [32001][256] f32   (pad row: u-prefetch overrun at t=249, batch 127)
//   C1b   [257][512] bf16    row k: col p<256 -> W12T[k][p]; p>=256 -> W11T[k][p-256]
//   C2b   [257][512] bf16    row k: col p<256 -> W22T[k][p]; p in [256,276) -> Wo[p-256][k]; else 0
//   Wi1p  [256][704] bf16    cols 700..703 zero (MFMA K-pad)
//   row 256 of C1b/C2b is all-zero (spike-list padding target)
//
// Final: R8 structure — two-track skewed pipeline (A = layer 1 @ t on waves
// 0-3, B = layer 2 @ t-1 + output @ t-2 on waves 4-7), wave-own spike lists
// (single ballot), ONE lgkm-only barrier per window, bf16 1KB-row tables
// (one dwordx4 per row per lane — the minimum load count; bf16 buffers are
// also what keeps the gather pipeline inside the VGPR budget, cf. R12's f32
// collapse). Ablation ledger (R9-R13) proved every other direction null or
// negative; window floor is issue + L2-gather latency + sync of the serial
// 250-step recurrence.
// ---------------------------------------------------------------------------
#define N_C  (257 * 512)
#define N_WP (256 * 704)

__global__ void prep_k(const float* __restrict__ Wi1, const float* __restrict__ W11,
                       const float* __restrict__ W12, const float* __restrict__ W22,
                       const float* __restrict__ Wo,
                       unsigned short* __restrict__ Wi1p, unsigned short* __restrict__ C1,
                       unsigned short* __restrict__ C2) {
    int idx = blockIdx.x * 256 + threadIdx.x;
    if (idx < N_C) {
        int k = idx >> 9, p = idx & 511;
        float v = 0.f;
        if (k < H) v = (p < 256) ? W12[p * H + k] : W11[(p - 256) * H + k];
        C1[idx] = f2b(v);
        return;
    }
    idx -= N_C;
    if (idx < N_C) {
        int k = idx >> 9, p = idx & 511;
        float v = 0.f;
        if (k < H) {
            if (p < 256) v = W22[p * H + k];
            else if (p - 256 < D_OUT) v = Wo[(p - 256) * H + k];
        }
        C2[idx] = f2b(v);
        return;
    }
    idx -= N_C;
    if (idx < N_WP) {
        int h = idx / 704, k = idx - h * 704;
        Wi1p[idx] = (k < D_IN) ? f2b(Wi1[h * D_IN + k]) : (unsigned short)0;
    }
}

// ---------------------------------------------------------------------------
// U = x @ Wi1^T + bi1 via MFMA 16x16x32 bf16 — proven, unchanged.
// ---------------------------------------------------------------------------
__global__ __launch_bounds__(256) void gemm_u_k(const float* __restrict__ x,
                                                const unsigned short* __restrict__ Wi1p,
                                                const float* __restrict__ bi1,
                                                float* __restrict__ U) {
    const int lane = threadIdx.x & 63;
    const int wv = threadIdx.x >> 6;
    const int quad = lane >> 4;
    const int nl = lane & 15;
    const int mbase = blockIdx.x * 64 + wv * 16;
    const int m = mbase + nl;

    f32x4 acc[16];
#pragma unroll
    for (int i = 0; i < 16; ++i) acc[i] = (f32x4)(0.f);

    float bias[16];
#pragma unroll
    for (int nt = 0; nt < 16; ++nt) bias[nt] = bi1[nt * 16 + nl];

    const float* xrow = x + (size_t)m * D_IN;
    const unsigned short* brow = Wi1p + nl * 704 + quad * 8;

    for (int k0 = 0; k0 < 704; k0 += 32) {
        int ka = k0 + quad * 8;
        int ka2 = (ka + 4 <= 696) ? ka + 4 : 696;
        float4 q0 = *(const float4*)(xrow + ka);
        float4 q1 = *(const float4*)(xrow + ka2);
        bf16x8 af;
        af[0] = (short)f2b(q0.x); af[1] = (short)f2b(q0.y);
        af[2] = (short)f2b(q0.z); af[3] = (short)f2b(q0.w);
        af[4] = (short)f2b(q1.x); af[5] = (short)f2b(q1.y);
        af[6] = (short)f2b(q1.z); af[7] = (short)f2b(q1.w);

        const unsigned short* bp = brow + k0;
        bf16x8 bf[16];
#pragma unroll
        for (int nt = 0; nt < 16; ++nt)
            bf[nt] = *(const bf16x8*)(bp + nt * 16 * 704);
#pragma unroll
        for (int nt = 0; nt < 16; ++nt)
            acc[nt] = __builtin_amdgcn_mfma_f32_16x16x32_bf16(af, bf[nt], acc[nt], 0, 0, 0);
    }

#pragma unroll
    for (int nt = 0; nt < 16; ++nt) {
#pragma unroll
        for (int r = 0; r < 4; ++r) {
            U[(size_t)(mbase + quad * 4 + r) * H + nt * 16 + nl] = acc[nt][r] + bias[nt];
        }
    }
}

// ---------------------------------------------------------------------------
// bf16 gather: wave's own list (<=64 rows + pads to mult of 8 -> zero row
// 256). One dwordx4 per row per lane (lane's 8 cols); 2x8-row rotation.
// Unpack: dword -> {lo<<16, hi&mask} as f32, packed v2f accumulate.
// ---------------------------------------------------------------------------
static __device__ __forceinline__ void ld8b(const unsigned* __restrict__ L, int c,
                                            const unsigned short* __restrict__ Cb,
                                            unsigned l8, u32x4* b) {
    uint4 ia = *(const uint4*)(L + c);
    uint4 ib = *(const uint4*)(L + c + 4);
    unsigned I[8] = {ia.x, ia.y, ia.z, ia.w, ib.x, ib.y, ib.z, ib.w};
#pragma unroll
    for (int jj = 0; jj < 8; ++jj)
        b[jj] = *(const u32x4*)(Cb + ((unsigned)I[jj] << 9) + l8);
}

static __device__ __forceinline__ void acc8b(const u32x4* b, v2f* a) {
#pragma unroll
    for (int jj = 0; jj < 8; ++jj) {
#pragma unroll
        for (int q = 0; q < 4; ++q) {
            unsigned u = b[jj][q];
            v2f t;
            t.x = __uint_as_float(u << 16);
            t.y = __uint_as_float(u & 0xffff0000u);
            a[q] += t;
        }
    }
}

static __device__ __forceinline__ void gatherB(const unsigned* __restrict__ L, int n,
                                               const unsigned short* __restrict__ Cb,
                                               unsigned l8, v2f* a) {
    a[0] = (v2f)(0.f); a[1] = (v2f)(0.f); a[2] = (v2f)(0.f); a[3] = (v2f)(0.f);
    int nr = (n + 7) & ~7;
    if (nr == 0) return;
    u32x4 x[8], y[8];
    ld8b(L, 0, Cb, l8, x);
    if (nr == 8) { acc8b(x, a); return; }
    ld8b(L, 8, Cb, l8, y);
    int c = 16;
    for (; c + 16 <= nr; c += 16) {
        acc8b(x, a); ld8b(L, c, Cb, l8, x);
        acc8b(y, a); ld8b(L, c + 8, Cb, l8, y);
    }
    if (nr - c == 8) {
        acc8b(x, a); ld8b(L, c, Cb, l8, x);
        acc8b(y, a); acc8b(x, a);
    } else {
        acc8b(x, a); acc8b(y, a);
    }
}

// ---------------------------------------------------------------------------
// Recurrent: one BLOCK (8 waves, 512 threads) per batch element.
// Waves 0-3 = track A (layer 1, step t), waves 4-7 = track B (layer 2, step
// t-1; wave 4 also runs the output chain at step t-2). 1 neuron per lane.
// One barrier per window.
// ---------------------------------------------------------------------------
__global__ __launch_bounds__(512, 1) void recurrent_k(
    const float* __restrict__ U,
    const float* __restrict__ mem1_0, const float* __restrict__ mem2_0,
    const float* __restrict__ memo_0,
    const float* __restrict__ b11v, const float* __restrict__ b12v,
    const float* __restrict__ b22v, const float* __restrict__ bov,
    const float* __restrict__ tau_adp_h1, const float* __restrict__ tau_adp_h2,
    const float* __restrict__ tau_m_h1, const float* __restrict__ tau_m_h2,
    const float* __restrict__ tau_m_o,
    const unsigned short* __restrict__ C1b, const unsigned short* __restrict__ C2b,
    float* __restrict__ out)
{
    const int tid = threadIdx.x;
    const int lane = tid & 63;
    const int w = tid >> 6;           // 0..7
    const bool trackA = (w < 4);
    const int wt = w & 3;             // wave-in-track
    const int bi = blockIdx.x;
    const int j = wt * 64 + lane;     // owned neuron (both layers)
    const unsigned l8 = (unsigned)lane * 8;   // ushort offset of lane's 8 cols

    __shared__ float PA[4][2][640];
    __shared__ float PB[4][3][640];
    __shared__ __align__(16) unsigned lists[8][128];

    for (int i = tid; i < 4 * 2 * 640; i += 512) ((float*)PA)[i] = 0.f;
    for (int i = tid; i < 4 * 3 * 640; i += 512) ((float*)PB)[i] = 0.f;
    __syncthreads();

    // ---- track A state (layer 1, scalar per lane) ----
    float mem1 = 0.f, b1 = 0.01f, spk1 = 0.f;
    float al1 = 0.f, ro1 = 0.f, oma1 = 0.f, omr1 = 0.f, b11p = 0.f;
    if (trackA) {
        mem1 = mem1_0[bi * H + j];
        al1 = __expf(-1.f / tau_m_h1[j]);
        ro1 = __expf(-1.f / tau_adp_h1[j]);
        oma1 = 1.f - al1; omr1 = 1.f - ro1;
        b11p = b11v[j];
    }

    // ---- track B state (layer 2) ----
    float mem2 = 0.f, b2 = 0.01f, spk2 = 0.f;
    float al2 = 0.f, ro2 = 0.f, oma2 = 0.f, omr2 = 0.f, bs2 = 0.f;
    if (!trackA) {
        mem2 = mem2_0[bi * H + j];
        al2 = __expf(-1.f / tau_m_h2[j]);
        ro2 = __expf(-1.f / tau_adp_h2[j]);
        oma2 = 1.f - al2; omr2 = 1.f - ro2;
        bs2 = b12v[j] + b22v[j];
    }

    // ---- wave-4 output state (1 output/lane, lanes 0..19) ----
    float memo = 0.f, alo = 0.f, omo = 0.f, bop = 0.f, acco = 0.f;
    const bool outl = (w == 4 && lane < D_OUT);
    if (outl) {
        memo = memo_0[bi * D_OUT + lane];
        alo = __expf(-1.f / tau_m_o[lane]);
        omo = 1.f - alo;
        bop = bov[lane];
    }

    const float* Up = U + (size_t)bi * T * H + j;
    float u_cur = trackA ? *Up : 0.f;
    float u_nxt = 0.f;
    const unsigned long long below = (1ull << lane) - 1ull;

    const int pidx_self = 320 + PIDX(j);   // PIDX(256 + j)
    const int pidx_j = PIDX(j);
    const int pidx_out = 320 + PIDX(lane); // PIDX(256 + lane), lanes < 20

    for (int t = 0; t < 252; ++t) {
        const int rbA = (t + 1) & 1;     // (t-1) & 1
        const int wbA = t & 1;
        const int rsB = (t + 1) % 3;     // (t-2) mod 3
        const int wsB = (t + 2) % 3;     // (t-1) mod 3

        if (trackA && t < 250) {
            float g11 = PA[0][rbA][pidx_self] + PA[1][rbA][pidx_self] +
                        PA[2][rbA][pidx_self] + PA[3][rbA][pidx_self];
            float h1 = u_cur + b11p + g11;
            b1 = ro1 * b1 + omr1 * spk1;
            float B1 = 0.01f + 1.8f * b1;
            mem1 = mem1 * al1 + oma1 * h1 - B1 * spk1;
            spk1 = (mem1 - B1 > 0.f) ? 1.f : 0.f;

            unsigned long long m = __ballot(spk1 != 0.f);
            int n = __popcll(m);
            unsigned* L = lists[w];
            if (spk1 != 0.f) L[__popcll(m & below)] = (unsigned)j;
            L[n + lane] = 256u;          // pads -> all-zero row
            asm volatile("s_waitcnt lgkmcnt(0)" ::: "memory");
            __builtin_amdgcn_wave_barrier();

            u_nxt = Up[H];               // pad row covers t=249 overrun
            Up += H;

            v2f a[4];
            gatherB(L, n, C1b, l8, a);

            float* pw = &PA[wt][wbA][10 * lane];
            *(v2f*)(pw + 0) = a[0];
            *(v2f*)(pw + 2) = a[1];
            *(v2f*)(pw + 4) = a[2];
            *(v2f*)(pw + 6) = a[3];
            u_cur = u_nxt;
        }

        if (w == 4 && t >= 2) {
            // output chain for step s = t-2
            float e = 0.f;
            if (lane < D_OUT) {
                float aO = PB[0][rsB][pidx_out] + PB[1][rsB][pidx_out] +
                           PB[2][rsB][pidx_out] + PB[3][rsB][pidx_out];
                memo = memo * alo + omo * (bop + aO);
                e = __expf(memo);
            }
            if (t >= 13) {
                float s = e;
#pragma unroll
                for (int dd = 16; dd >= 1; dd >>= 1) s += __shfl_xor(s, dd, 32);
                if (lane < D_OUT) acco += __fdividef(e, s);
            }
        }

        if (!trackA && t >= 1 && t < 251) {
            // update2(t-1): g12 from G1(t-1), g22 from G2(t-2)
            float g12 = PA[0][rbA][pidx_j] + PA[1][rbA][pidx_j] +
                        PA[2][rbA][pidx_j] + PA[3][rbA][pidx_j];
            float g22 = PB[0][rsB][pidx_j] + PB[1][rsB][pidx_j] +
                        PB[2][rsB][pidx_j] + PB[3][rsB][pidx_j];
            float h2 = bs2 + g22 + g12;
            b2 = ro2 * b2 + omr2 * spk2;
            float B2 = 0.01f + 1.8f * b2;
            mem2 = mem2 * al2 + oma2 * h2 - B2 * spk2;
            spk2 = (mem2 - B2 > 0.f) ? 1.f : 0.f;

            unsigned long long m = __ballot(spk2 != 0.f);
            int n = __popcll(m);
            unsigned* L = lists[w];
            if (spk2 != 0.f) L[__popcll(m & below)] = (unsigned)j;
            L[n + lane] = 256u;
            asm volatile("s_waitcnt lgkmcnt(0)" ::: "memory");
            __builtin_amdgcn_wave_barrier();

            v2f a[4];
            gatherB(L, n, C2b, l8, a);

            float* pw = &PB[wt][wsB][10 * lane];
            *(v2f*)(pw + 0) = a[0];
            *(v2f*)(pw + 2) = a[1];
            *(v2f*)(pw + 4) = a[2];
            *(v2f*)(pw + 6) = a[3];
        }

        bar();   // single barrier per window
    }

    if (outl) out[bi * D_OUT + lane] = acco;
}

// ---------------------------------------------------------------------------
extern "C" void kernel_launch(void* const* d_in, const int* in_sizes, int n_in,
                              void* d_out, int out_size, void* d_ws, size_t ws_size,
                              hipStream_t stream) {
    const float* x          = (const float*)d_in[0];
    const float* mem1_0     = (const float*)d_in[1];
    const float* mem2_0     = (const float*)d_in[2];
    const float* memo_0     = (const float*)d_in[3];
    const float* Wi1        = (const float*)d_in[4];
    const float* bi1        = (const float*)d_in[5];
    const float* W11        = (const float*)d_in[6];
    const float* b11        = (const float*)d_in[7];
    const float* W12        = (const float*)d_in[8];
    const float* b12        = (const float*)d_in[9];
    const float* W22        = (const float*)d_in[10];
    const float* b22        = (const float*)d_in[11];
    const float* Wo         = (const float*)d_in[12];
    const float* bo         = (const float*)d_in[13];
    const float* tau_adp_h1 = (const float*)d_in[14];
    const float* tau_adp_h2 = (const float*)d_in[15];
    const float* tau_m_h1   = (const float*)d_in[16];
    const float* tau_m_h2   = (const float*)d_in[17];
    const float* tau_m_o    = (const float*)d_in[18];

    float* U = (float*)d_ws;                                       // [32001][256] f32
    unsigned short* C1b = (unsigned short*)(U + ((size_t)BATCH * T + 1) * H);
    unsigned short* C2b = C1b + N_C;
    unsigned short* Wi1p = C2b + N_C;

    int prep_total = 2 * N_C + N_WP;
    prep_k<<<(prep_total + 255) / 256, 256, 0, stream>>>(
        Wi1, W11, W12, W22, Wo, Wi1p, C1b, C2b);

    gemm_u_k<<<(BATCH * T) / 64, 256, 0, stream>>>(x, Wi1p, bi1, U);

    recurrent_k<<<BATCH, 512, 0, stream>>>(U, mem1_0, mem2_0, memo_0,
                                           b11, b12, b22, bo,
                                           tau_adp_h1, tau_adp_h2,
                                           tau_m_h1, tau_m_h2, tau_m_o,
                                           C1b, C2b, (float*)d_out);
}